// Round 7
// baseline (948.486 us; speedup 1.0000x reference)
//
#include <hip/hip_runtime.h>
#include <hip/hip_bf16.h>
#include <cstdint>
#include <cstddef>

typedef __attribute__((ext_vector_type(8))) short sv8;
typedef __attribute__((ext_vector_type(4))) short sv4;
typedef __attribute__((ext_vector_type(4))) float f32x4;

__device__ __forceinline__ float bf2f(short s) {
    unsigned u = ((unsigned)(unsigned short)s) << 16;
    return __builtin_bit_cast(float, u);
}
// Manual RNE (used in cold kernels only)
__device__ __forceinline__ short f2bf(float f) {
    unsigned u = __builtin_bit_cast(unsigned, f);
    u = (u + 0x7fffu + ((u >> 16) & 1u)) >> 16;
    return (short)u;
}
// Intrinsic RNE cast — compiler generates v_cvt_pk_bf16_f32 for pairs (m240)
__device__ __forceinline__ short f2bf_i(float f) {
    __hip_bfloat16 h = __float2bfloat16(f);
    return __builtin_bit_cast(short, h);
}

// ---------------------------------------------------------------------------
// Kernel 0: W_out [1024][1025] fp32 -> Wt bf16 [1152][1024] (transposed,
// zero-padded rows 1025..1151). 64x64 LDS tile transpose.
// grid (18, 16), block 256.
// ---------------------------------------------------------------------------
__global__ __launch_bounds__(256) void wtrans_kernel(
    const float* __restrict__ Wo, short* __restrict__ Wt)
{
    __shared__ float T[64][65];
    const int tid = threadIdx.x;
    const int n0 = blockIdx.x * 64;   // output-col dim (vocab), padded to 1152
    const int k0 = blockIdx.y * 64;   // joint dim (1024)
    const int nl = tid & 63;
    const int kb = (tid >> 6) * 16;
#pragma unroll
    for (int r = 0; r < 16; ++r) {
        int kl = kb + r;
        int n = n0 + nl;
        T[kl][nl] = (n < 1025) ? Wo[(size_t)(k0 + kl) * 1025 + n] : 0.f;
    }
    __syncthreads();
    const int wn = tid >> 2;
    const int kc = (tid & 3) * 16;
    sv8 s0, s1;
#pragma unroll
    for (int j = 0; j < 8; ++j) {
        s0[j] = f2bf(T[kc + j][wn]);
        s1[j] = f2bf(T[kc + 8 + j][wn]);
    }
    short* dst = Wt + (size_t)(n0 + wn) * 1024 + k0 + kc;
    *(sv8*)dst = s0;
    *(sv8*)(dst + 8) = s1;
}

// ---------------------------------------------------------------------------
// Projection GEMM: outb[M][1024] = bf16( X[M][K] @ W[K][1024] + bias )
// BM=128, BN=128, BK=32. 256 threads = 4 waves (2x2), each wave 64x64.
// grid (M/128, 8).
// ---------------------------------------------------------------------------
template<int K>
__global__ __launch_bounds__(256) void proj_gemm(
    const float* __restrict__ X, const float* __restrict__ W,
    const float* __restrict__ bias, short* __restrict__ outb)
{
    __shared__ short As[128 * 40];  // [row][k], pad to 40
    __shared__ short Bs[128 * 40];  // [n][k] (transposed), pad to 40

    const int tid = threadIdx.x;
    const int m0 = blockIdx.x * 128;
    const int n0 = blockIdx.y * 128;
    const int lane = tid & 63;
    const int wid = tid >> 6;
    const int wr = wid >> 1, wc = wid & 1;

    f32x4 acc[4][4];
#pragma unroll
    for (int i = 0; i < 4; ++i)
#pragma unroll
        for (int j = 0; j < 4; ++j)
#pragma unroll
            for (int q = 0; q < 4; ++q) acc[i][j][q] = 0.f;

    const int sr = tid >> 3;         // A staging: base row (0..31)
    const int sc4 = (tid & 7) * 4;   // A staging: float col
    const int bn = tid >> 1;         // B staging: n row (0..127)
    const int kh = (tid & 1) * 16;   // B staging: k half

    for (int kt = 0; kt < K / 32; ++kt) {
        const int k0 = kt * 32;
        __syncthreads();
        // stage A: [128][32] fp32 -> bf16
#pragma unroll
        for (int r = 0; r < 4; ++r) {
            int row = sr + r * 32;
            f32x4 xv = *(const f32x4*)(X + (size_t)(m0 + row) * K + k0 + sc4);
            sv4 a;
#pragma unroll
            for (int q = 0; q < 4; ++q) a[q] = f2bf(xv[q]);
            *(sv4*)(As + row * 40 + sc4) = a;
        }
        // stage B transposed: Bs[n][k] = bf16(W[k0+k][n0+n])
        {
            const float* wp = W + (size_t)(k0 + kh) * 1024 + n0 + bn;
            sv8 b0, b1;
#pragma unroll
            for (int j = 0; j < 8; ++j) b0[j] = f2bf(wp[(size_t)j * 1024]);
#pragma unroll
            for (int j = 0; j < 8; ++j) b1[j] = f2bf(wp[(size_t)(8 + j) * 1024]);
            *(sv8*)(Bs + bn * 40 + kh) = b0;
            *(sv8*)(Bs + bn * 40 + kh + 8) = b1;
        }
        __syncthreads();
        // compute
        const int fr = lane & 15;
        const int fk = (lane >> 4) * 8;
        sv8 af[4], bfr[4];
#pragma unroll
        for (int mi = 0; mi < 4; ++mi)
            af[mi] = *(const sv8*)(As + (wr * 64 + mi * 16 + fr) * 40 + fk);
#pragma unroll
        for (int ni = 0; ni < 4; ++ni)
            bfr[ni] = *(const sv8*)(Bs + (wc * 64 + ni * 16 + fr) * 40 + fk);
#pragma unroll
        for (int mi = 0; mi < 4; ++mi)
#pragma unroll
            for (int ni = 0; ni < 4; ++ni)
                acc[mi][ni] = __builtin_amdgcn_mfma_f32_16x16x32_bf16(
                    af[mi], bfr[ni], acc[mi][ni], 0, 0, 0);
    }

    // epilogue: +bias, bf16 store
    const int fr = lane & 15;
    const int fq = lane >> 4;
#pragma unroll
    for (int ni = 0; ni < 4; ++ni) {
        int col = n0 + wc * 64 + ni * 16 + fr;
        float bv = bias[col];
#pragma unroll
        for (int mi = 0; mi < 4; ++mi) {
            int rowb = m0 + wr * 64 + mi * 16 + fq * 4;
#pragma unroll
            for (int q = 0; q < 4; ++q)
                outb[(size_t)(rowb + q) * 1024 + col] = f2bf(acc[mi][ni][q] + bv);
        }
    }
}

// ---------------------------------------------------------------------------
// Main joint GEMM: out[m=(b,t,u)][v] = relu(encb[b,t,:] + predb[b,u,:]) @ Wt + b_out
// M-tile = 128 rows = one (b,t) x all 128 u. BN=288 (1152 = 4*288 exactly,
// cuts A-tile rebuild redundancy 9x -> 4x). BK=64.
// 256 threads = 4 waves (2x2), wave computes 64x144 via 4x9 frags of 16x16x32.
// LDS: A 128*72*2=18432 + B 288*72*2=41472 = 59904 B -> 2 blocks/CU.
// grid (4, 1024): x = n-tile, y = m-tile (= b*256+t).
// ---------------------------------------------------------------------------
__global__ __launch_bounds__(256, 2) void joint_gemm(
    const short* __restrict__ encb,   // [1024][1024] bf16
    const short* __restrict__ predb,  // [512][1024] bf16
    const short* __restrict__ Wt,     // [1152][1024] bf16 (n-major)
    const float* __restrict__ b_out,  // [1025]
    float* __restrict__ out)          // [131072][1025]
{
    __shared__ short As[128 * 72];  // [u][k], pad 72
    __shared__ short Bs[288 * 72];  // [n][k], pad 72

    const int tid = threadIdx.x;
    const int n0 = blockIdx.x * 288;
    const int mtile = blockIdx.y;       // = b*256 + t
    const int bIdx = mtile >> 8;
    const int lane = tid & 63;
    const int wid = tid >> 6;
    const int wr = wid >> 1, wc = wid & 1;

    f32x4 acc[4][9];
#pragma unroll
    for (int i = 0; i < 4; ++i)
#pragma unroll
        for (int j = 0; j < 9; ++j)
#pragma unroll
            for (int q = 0; q < 4; ++q) acc[i][j][q] = 0.f;

    const int su = tid >> 3;          // staging row base (0..31)
    const int sk8 = (tid & 7) * 8;    // staging k offset (bf16)
    const short* encRow = encb + (size_t)mtile * 1024;
    const short* predBase = predb + (size_t)(bIdx * 128) * 1024;

    for (int kt = 0; kt < 16; ++kt) {
        const int k0 = kt * 64;
        __syncthreads();
        // --- stage A: As[u][k] = bf16(relu(enc[k] + pred[u][k])) ---
        sv8 ev = *(const sv8*)(encRow + k0 + sk8);
        float ef[8];
#pragma unroll
        for (int i = 0; i < 8; ++i) ef[i] = bf2f(ev[i]);
#pragma unroll
        for (int r = 0; r < 4; ++r) {
            int u = su + r * 32;
            sv8 pv = *(const sv8*)(predBase + (size_t)u * 1024 + k0 + sk8);
            sv8 av;
#pragma unroll
            for (int i = 0; i < 8; ++i)
                av[i] = f2bf_i(fmaxf(ef[i] + bf2f(pv[i]), 0.f));
            *(sv8*)(As + u * 72 + sk8) = av;
        }
        // --- stage B: Bs[n][k] = Wt[n0+n][k0+k] (already bf16), 288 rows ---
#pragma unroll
        for (int r = 0; r < 9; ++r) {
            int n = su + r * 32;
            sv8 wv = *(const sv8*)(Wt + (size_t)(n0 + n) * 1024 + k0 + sk8);
            *(sv8*)(Bs + n * 72 + sk8) = wv;
        }
        __syncthreads();
        // --- compute: 2 k-substeps of 32, 36 MFMA each ---
        const int fr = lane & 15;
        const int fk = (lane >> 4) * 8;
#pragma unroll
        for (int ks = 0; ks < 2; ++ks) {
            sv8 af[4], bfr[9];
#pragma unroll
            for (int mi = 0; mi < 4; ++mi)
                af[mi] = *(const sv8*)(As + (wr * 64 + mi * 16 + fr) * 72 + ks * 32 + fk);
#pragma unroll
            for (int ni = 0; ni < 9; ++ni)
                bfr[ni] = *(const sv8*)(Bs + (wc * 144 + ni * 16 + fr) * 72 + ks * 32 + fk);
#pragma unroll
            for (int mi = 0; mi < 4; ++mi)
#pragma unroll
                for (int ni = 0; ni < 9; ++ni)
                    acc[mi][ni] = __builtin_amdgcn_mfma_f32_16x16x32_bf16(
                        af[mi], bfr[ni], acc[mi][ni], 0, 0, 0);
        }
    }

    // --- epilogue: + b_out, fp32 store, predicated on v < 1025 ---
    const size_t m0 = (size_t)mtile * 128;
    const int fr = lane & 15;
    const int fq = lane >> 4;
#pragma unroll
    for (int ni = 0; ni < 9; ++ni) {
        int v = n0 + wc * 144 + ni * 16 + fr;
        if (v < 1025) {
            float bias = b_out[v];
#pragma unroll
            for (int mi = 0; mi < 4; ++mi) {
                int urow = wr * 64 + mi * 16 + fq * 4;
#pragma unroll
                for (int q = 0; q < 4; ++q)
                    out[(m0 + urow + q) * 1025 + v] = acc[mi][ni][q] + bias;
            }
        }
    }
}

// ---------------------------------------------------------------------------
extern "C" void kernel_launch(void* const* d_in, const int* in_sizes, int n_in,
                              void* d_out, int out_size, void* d_ws, size_t ws_size,
                              hipStream_t stream) {
    const float* enc    = (const float*)d_in[0];  // [4,256,512]
    const float* pred   = (const float*)d_in[1];  // [4,128,640]
    const float* W_enc  = (const float*)d_in[2];  // [512,1024]
    const float* b_enc  = (const float*)d_in[3];  // [1024]
    const float* W_pred = (const float*)d_in[4];  // [640,1024]
    const float* b_pred = (const float*)d_in[5];  // [1024]
    const float* W_out  = (const float*)d_in[6];  // [1024,1025]
    const float* b_out  = (const float*)d_in[7];  // [1025]
    float* out = (float*)d_out;

    // Workspace layout (bytes):
    //   Wt    : 1152*1024*2 = 2359296
    //   encb  : 1024*1024*2 = 2097152
    //   predb :  512*1024*2 = 1048576
    //   total : 5505024
    if (ws_size < 5505024) return;  // fail cleanly (poisoned out) instead of OOB-faulting the GPU
    char* ws = (char*)d_ws;
    short* Wt    = (short*)ws;
    short* encb  = (short*)(ws + 2359296);
    short* predb = (short*)(ws + 2359296 + 2097152);

    wtrans_kernel<<<dim3(18, 16), 256, 0, stream>>>(W_out, Wt);
    proj_gemm<512><<<dim3(8, 8), 256, 0, stream>>>(enc, W_enc, b_enc, encb);
    proj_gemm<640><<<dim3(4, 8), 256, 0, stream>>>(pred, W_pred, b_pred, predb);
    joint_gemm<<<dim3(4, 1024), 256, 0, stream>>>(encb, predb, Wt, b_out, out);
}